// Round 4
// baseline (43.474 us; speedup 1.0000x reference)
//
#include <hip/hip_runtime.h>
#include <math.h>

#define NQ      100
#define BS      8
#define NC      4
#define NPTS    30
#define NTGT    512
#define P_TOTAL (NQ*BS)   /* 800 */
#define TILE_P  8
#define TILE_T  32
#define NTHREADS 256

typedef float f32x2 __attribute__((ext_vector_type(2)));

// packed rotated sub: (a.s - b.s, a.r - b.r) in ONE v_pk_add_f32
__device__ __forceinline__ f32x2 pksub(f32x2 a, f32x2 b) {
    f32x2 r;
    asm("v_pk_add_f32 %0, %1, %2 neg_lo:[0,1] neg_hi:[0,1]"
        : "=v"(r) : "v"(a), "v"(b));
    return r;
}
// Chebyshev of rotated deltas == L1 of original: max(|ds|,|dr|) in ONE VOP3
__device__ __forceinline__ float maxabs2(f32x2 w) {
    float d;
    asm("v_max_f32 %0, abs(%1), abs(%2)" : "=v"(d) : "v"(w.x), "v"(w.y));
    return d;
}
__device__ __forceinline__ float min3f(float a, float b, float c) {
    float r;
    asm("v_min3_f32 %0, %1, %2, %3" : "=v"(r) : "v"(a), "v"(b), "v"(c));
    return r;
}

// 2nd arg = min waves per EU = 4  =>  VGPR cap 128: enough to keep
// st[30] (60) + m2[30] (30) + temps live WITHOUT LDS rematerialization.
__global__ __launch_bounds__(NTHREADS, 4) void matcher_kernel(
    const float* __restrict__ logits,      // [800,4]
    const float* __restrict__ pred_poly,   // [800,30,2]
    const int*   __restrict__ tgt_ids,     // [512]
    const float* __restrict__ tgt_poly,    // [512,30,2]
    float*       __restrict__ out)         // [800,512]
{
    // rotated coords: s = x+y, r = x-y  =>  L1 dist = max(|ds|, |dr|)
    __shared__ f32x2 srt_t[NPTS][TILE_T + 1];
    __shared__ f32x2 srt_p[TILE_P][NPTS];
    __shared__ float prob_lds[TILE_P][NC];

    const int tid = threadIdx.x;
    const int p0  = blockIdx.x * TILE_P;
    const int t0  = blockIdx.y * TILE_T;

    // ---- stage 32 tgt polylines, rotate into (s,r) ----
    for (int idx = tid; idx < TILE_T * NPTS; idx += NTHREADS) {
        const int tt = idx / NPTS;
        const int j  = idx - tt * NPTS;
        const float2 v = *reinterpret_cast<const float2*>(
            tgt_poly + (size_t)(t0 + tt) * (NPTS * 2) + j * 2);
        srt_t[j][tt] = f32x2{v.x + v.y, v.x - v.y};
    }
    // ---- stage 8 pred polylines, rotate ----
    for (int idx = tid; idx < TILE_P * NPTS; idx += NTHREADS) {
        const int pp = idx / NPTS;
        const int i  = idx - pp * NPTS;
        const float2 v = *reinterpret_cast<const float2*>(
            pred_poly + (size_t)(p0 + pp) * (NPTS * 2) + i * 2);
        srt_p[pp][i] = f32x2{v.x + v.y, v.x - v.y};
    }
    // ---- softmax over 4 classes ----
    if (tid < TILE_P) {
        const float* l = logits + (size_t)(p0 + tid) * NC;
        const float a0 = l[0], a1 = l[1], a2 = l[2], a3 = l[3];
        const float m  = fmaxf(fmaxf(a0, a1), fmaxf(a2, a3));
        const float e0 = expf(a0 - m), e1 = expf(a1 - m);
        const float e2 = expf(a2 - m), e3 = expf(a3 - m);
        const float inv = 1.0f / (e0 + e1 + e2 + e3);
        prob_lds[tid][0] = e0 * inv;
        prob_lds[tid][1] = e1 * inv;
        prob_lds[tid][2] = e2 * inv;
        prob_lds[tid][3] = e3 * inv;
    }
    __syncthreads();

    const int tl = tid & (TILE_T - 1);
    const int pl = tid >> 5;

    // my tgt polyline (rotated) in registers: 30 x f32x2 = 60 VGPRs, live across i-loop
    f32x2 st[NPTS];
#pragma unroll
    for (int j = 0; j < NPTS; ++j) st[j] = srt_t[j][tl];

    float m2[NPTS];
#pragma unroll
    for (int j = 0; j < NPTS; ++j) m2[j] = 1e30f;

    float sum1 = 0.0f;
    // ROLLED i-loop (I$-friendly ~190-instr body); j fully unrolled (static reg idx)
#pragma unroll 1
    for (int i = 0; i < NPTS; i += 2) {
        const f32x2 pr0 = srt_p[pl][i];
        const f32x2 pr1 = srt_p[pl][i + 1];
        float dmin0 = 1e30f, dmin1 = 1e30f;
#pragma unroll
        for (int j = 0; j < NPTS; j += 2) {
            const float d00 = maxabs2(pksub(pr0, st[j]));
            const float d01 = maxabs2(pksub(pr0, st[j + 1]));
            const float d10 = maxabs2(pksub(pr1, st[j]));
            const float d11 = maxabs2(pksub(pr1, st[j + 1]));
            m2[j]     = min3f(m2[j],     d00, d10);
            m2[j + 1] = min3f(m2[j + 1], d01, d11);
            dmin0     = min3f(dmin0, d00, d01);
            dmin1     = min3f(dmin1, d10, d11);
        }
        sum1 += dmin0;
        sum1 += dmin1;
    }
    float sum2 = 0.0f;
#pragma unroll
    for (int j = 0; j < NPTS; ++j) sum2 += m2[j];

    const int   t   = t0 + tl;
    const int   cls = tgt_ids[t];
    const float cc  = -prob_lds[pl][cls];
    out[(size_t)(p0 + pl) * NTGT + t] = cc + (sum1 + sum2) * (0.5f / (float)NPTS);
}

extern "C" void kernel_launch(void* const* d_in, const int* in_sizes, int n_in,
                              void* d_out, int out_size, void* d_ws, size_t ws_size,
                              hipStream_t stream) {
    const float* logits    = (const float*)d_in[0];
    const float* pred_poly = (const float*)d_in[1];
    const int*   tids      = (const int*)d_in[2];
    const float* tgt_poly  = (const float*)d_in[3];
    float*       out       = (float*)d_out;

    dim3 grid(P_TOTAL / TILE_P, NTGT / TILE_T);  // (100, 16)
    dim3 block(NTHREADS);
    matcher_kernel<<<grid, block, 0, stream>>>(logits, pred_poly, tids, tgt_poly, out);
}

// Round 5
// 43.436 us; speedup vs baseline: 1.0009x; 1.0009x over previous
//
#include <hip/hip_runtime.h>
#include <math.h>

#define NQ      100
#define BS      8
#define NC      4
#define NPTS    30
#define NTGT    512
#define P_TOTAL (NQ*BS)   /* 800 */
#define TILE_P  8
#define TILE_T  32
#define NTHREADS 256

typedef float f32x2 __attribute__((ext_vector_type(2)));

// packed rotated sub: (a.s - b.s, a.r - b.r) in ONE v_pk_add_f32
__device__ __forceinline__ f32x2 pksub(f32x2 a, f32x2 b) {
    f32x2 r;
    asm("v_pk_add_f32 %0, %1, %2 neg_lo:[0,1] neg_hi:[0,1]"
        : "=v"(r) : "v"(a), "v"(b));
    return r;
}
// Chebyshev of rotated deltas == L1 of original: max(|ds|,|dr|) in ONE VOP3
__device__ __forceinline__ float maxabs2(f32x2 w) {
    float d;
    asm("v_max_f32 %0, abs(%1), abs(%2)" : "=v"(d) : "v"(w.x), "v"(w.y));
    return d;
}
__device__ __forceinline__ float min3f(float a, float b, float c) {
    float r;
    asm("v_min3_f32 %0, %1, %2, %3" : "=v"(r) : "v"(a), "v"(b), "v"(c));
    return r;
}

// Pin occupancy to EXACTLY 4 waves/EU => 128-VGPR budget. launch_bounds' 2nd
// arg only sets the MIN; the scheduler still remats LDS loads to hit 8 waves
// (R3: VGPR stayed 56). waves_per_eu(4,4) stops that.
__global__ __launch_bounds__(NTHREADS)
__attribute__((amdgpu_waves_per_eu(4, 4)))
void matcher_kernel(
    const float* __restrict__ logits,      // [800,4]
    const float* __restrict__ pred_poly,   // [800,30,2]
    const int*   __restrict__ tgt_ids,     // [512]
    const float* __restrict__ tgt_poly,    // [512,30,2]
    float*       __restrict__ out)         // [800,512]
{
    // rotated coords: s = x+y, r = x-y  =>  L1 dist = max(|ds|, |dr|)
    __shared__ f32x2 srt_t[NPTS][TILE_T + 1];
    __shared__ f32x2 srt_p[TILE_P][NPTS];
    __shared__ float prob_lds[TILE_P][NC];

    const int tid = threadIdx.x;
    const int p0  = blockIdx.x * TILE_P;
    const int t0  = blockIdx.y * TILE_T;

    // ---- stage 32 tgt polylines, rotate into (s,r) ----
    for (int idx = tid; idx < TILE_T * NPTS; idx += NTHREADS) {
        const int tt = idx / NPTS;
        const int j  = idx - tt * NPTS;
        const float2 v = *reinterpret_cast<const float2*>(
            tgt_poly + (size_t)(t0 + tt) * (NPTS * 2) + j * 2);
        srt_t[j][tt] = f32x2{v.x + v.y, v.x - v.y};
    }
    // ---- stage 8 pred polylines, rotate ----
    for (int idx = tid; idx < TILE_P * NPTS; idx += NTHREADS) {
        const int pp = idx / NPTS;
        const int i  = idx - pp * NPTS;
        const float2 v = *reinterpret_cast<const float2*>(
            pred_poly + (size_t)(p0 + pp) * (NPTS * 2) + i * 2);
        srt_p[pp][i] = f32x2{v.x + v.y, v.x - v.y};
    }
    // ---- softmax over 4 classes ----
    if (tid < TILE_P) {
        const float* l = logits + (size_t)(p0 + tid) * NC;
        const float a0 = l[0], a1 = l[1], a2 = l[2], a3 = l[3];
        const float m  = fmaxf(fmaxf(a0, a1), fmaxf(a2, a3));
        const float e0 = expf(a0 - m), e1 = expf(a1 - m);
        const float e2 = expf(a2 - m), e3 = expf(a3 - m);
        const float inv = 1.0f / (e0 + e1 + e2 + e3);
        prob_lds[tid][0] = e0 * inv;
        prob_lds[tid][1] = e1 * inv;
        prob_lds[tid][2] = e2 * inv;
        prob_lds[tid][3] = e3 * inv;
    }
    __syncthreads();

    const int tl = tid & (TILE_T - 1);
    const int pl = tid >> 5;

    // my tgt polyline (rotated) in registers: 30 x f32x2 = 60 VGPRs
    f32x2 st[NPTS];
#pragma unroll
    for (int j = 0; j < NPTS; ++j) {
        st[j] = srt_t[j][tl];
        // anti-remat pin: an asm def with 15 downstream uses cannot be
        // rematerialized/sunk into the i-loop (R3 showed the allocator
        // re-reads LDS inside the loop otherwise).
        asm("" : "+v"(st[j]));
    }

    float m2[NPTS];
#pragma unroll
    for (int j = 0; j < NPTS; ++j) m2[j] = 1e30f;

    float sum1 = 0.0f;
    // ROLLED i-loop; j fully unrolled (static reg indexing)
#pragma unroll 1
    for (int i = 0; i < NPTS; i += 2) {
        const f32x2 pr0 = srt_p[pl][i];
        const f32x2 pr1 = srt_p[pl][i + 1];
        float dmin0 = 1e30f, dmin1 = 1e30f;
#pragma unroll
        for (int j = 0; j < NPTS; j += 2) {
            const float d00 = maxabs2(pksub(pr0, st[j]));
            const float d01 = maxabs2(pksub(pr0, st[j + 1]));
            const float d10 = maxabs2(pksub(pr1, st[j]));
            const float d11 = maxabs2(pksub(pr1, st[j + 1]));
            m2[j]     = min3f(m2[j],     d00, d10);
            m2[j + 1] = min3f(m2[j + 1], d01, d11);
            dmin0     = min3f(dmin0, d00, d01);
            dmin1     = min3f(dmin1, d10, d11);
        }
        sum1 += dmin0;
        sum1 += dmin1;
    }
    float sum2 = 0.0f;
#pragma unroll
    for (int j = 0; j < NPTS; ++j) sum2 += m2[j];

    const int   t   = t0 + tl;
    const int   cls = tgt_ids[t];
    const float cc  = -prob_lds[pl][cls];
    out[(size_t)(p0 + pl) * NTGT + t] = cc + (sum1 + sum2) * (0.5f / (float)NPTS);
}

extern "C" void kernel_launch(void* const* d_in, const int* in_sizes, int n_in,
                              void* d_out, int out_size, void* d_ws, size_t ws_size,
                              hipStream_t stream) {
    const float* logits    = (const float*)d_in[0];
    const float* pred_poly = (const float*)d_in[1];
    const int*   tids      = (const int*)d_in[2];
    const float* tgt_poly  = (const float*)d_in[3];
    float*       out       = (float*)d_out;

    dim3 grid(P_TOTAL / TILE_P, NTGT / TILE_T);  // (100, 16)
    dim3 block(NTHREADS);
    matcher_kernel<<<grid, block, 0, stream>>>(logits, pred_poly, tids, tgt_poly, out);
}